// Round 5
// baseline (147.115 us; speedup 1.0000x reference)
//
#include <hip/hip_runtime.h>
#include <math.h>

#define NROWS 4096
#define DIM   512
#define BT    64            // block tile: 64x64, 4 waves split K
#define NTILE (NROWS / BT)  // 64
#define NBLK  (NTILE * (NTILE + 1) / 2)  // 2080 triangular blocks

typedef __attribute__((ext_vector_type(4))) float f32x4;
typedef __attribute__((ext_vector_type(8))) short bf16x8;

// ws layout (bytes):
// [0,       16384)   float mag[4096]
// [16384,   32768)   float row_neg[4096]
// [32768,   32776)   double loss
// [32776,   32780)   unsigned int pair_cnt
// [32800,   4227104) unsigned short Xb[4096*512]  (bf16 copy of X)
// [4227104, ...)     pairs: 3 ints each {i, j, float_bits(dist)}
#define XB_OFF   32800
#define PAIR_OFF 4227104

__device__ inline unsigned short f2bf(float f) {
    unsigned int u = __float_as_uint(f);
    unsigned int r = (u + 0x7fffu + ((u >> 16) & 1u)) >> 16;   // RTNE
    return (unsigned short)r;
}

// fused: bf16 convert + row sq-norms (reads X once)
__global__ void prep_kernel(const float* __restrict__ X,
                            unsigned short* __restrict__ Xb,
                            float* __restrict__ mag) {
    int row  = blockIdx.x * 4 + (threadIdx.x >> 6);
    int lane = threadIdx.x & 63;
    const float4* p = reinterpret_cast<const float4*>(X + (size_t)row * DIM);
    short4* o = reinterpret_cast<short4*>(Xb + (size_t)row * DIM);
    float s = 0.f;
#pragma unroll
    for (int q = lane; q < DIM / 4; q += 64) {
        float4 v = p[q];
        s += v.x * v.x + v.y * v.y + v.z * v.z + v.w * v.w;
        short4 b;
        b.x = (short)f2bf(v.x); b.y = (short)f2bf(v.y);
        b.z = (short)f2bf(v.z); b.w = (short)f2bf(v.w);
        o[q] = b;
    }
#pragma unroll
    for (int off = 32; off; off >>= 1) s += __shfl_down(s, off);
    if (lane == 0) mag[row] = s;
}

// K-split MFMA GEMM: block = 64x64 tile, wave w does K in [128w, 128w+128),
// LDS all-to-all reduction, then wave w owns rows [16w, 16w+16).
__global__ __launch_bounds__(256) void sim_ksplit(
        const unsigned short* __restrict__ Xb, const int* __restrict__ tgt,
        const float* __restrict__ mag, float* __restrict__ row_neg,
        unsigned int* __restrict__ pair_cnt, int* __restrict__ pairs,
        unsigned int cap) {
    __shared__ f32x4 red[4][3][4][64];   // [m][slot][n][lane] = 48 KB

    const int tid  = threadIdx.x;
    const int lane = tid & 63;
    const int wid  = tid >> 6;        // 4 waves, K-offset = wid*128
    const int l15  = lane & 15;
    const int lg   = lane >> 4;       // 0..3

    // triangular block mapping: t -> (bi, bj), bi <= bj (NTILE=64)
    int t = blockIdx.x;
    int bi = (int)((129.0f - sqrtf(16641.0f - 8.0f * (float)t)) * 0.5f);
    if (bi < 0) bi = 0;
    if (bi > NTILE - 1) bi = NTILE - 1;
    while ((129 * (bi + 1) - (bi + 1) * (bi + 1)) / 2 <= t) bi++;
    while ((129 * bi - bi * bi) / 2 > t) bi--;
    int bj = bi + (t - (129 * bi - bi * bi) / 2);
    const int rowBase = bi * BT;
    const int colBase = bj * BT;
    const bool offd = (bi != bj);

    f32x4 acc[4][4];
#pragma unroll
    for (int m = 0; m < 4; m++)
#pragma unroll
        for (int n = 0; n < 4; n++) acc[m][n] = (f32x4){0.f, 0.f, 0.f, 0.f};

    // per-lane fragment base (A and B have the same pattern):
    // lane (lg,l15) reads 16B at X[base + l15][k0 + lg*8]
    const unsigned short* pA = Xb + (size_t)(rowBase + l15) * DIM + wid * 128 + lg * 8;
    const unsigned short* pB = Xb + (size_t)(colBase + l15) * DIM + wid * 128 + lg * 8;

#define LOADF(da, db, kt)                                                     \
    {                                                                         \
        const int ko = (kt) * 32;                                             \
        da[0] = *reinterpret_cast<const bf16x8*>(pA + 0 * 16 * DIM + ko);     \
        da[1] = *reinterpret_cast<const bf16x8*>(pA + 1 * 16 * DIM + ko);     \
        da[2] = *reinterpret_cast<const bf16x8*>(pA + 2 * 16 * DIM + ko);     \
        da[3] = *reinterpret_cast<const bf16x8*>(pA + 3 * 16 * DIM + ko);     \
        db[0] = *reinterpret_cast<const bf16x8*>(pB + 0 * 16 * DIM + ko);     \
        db[1] = *reinterpret_cast<const bf16x8*>(pB + 1 * 16 * DIM + ko);     \
        db[2] = *reinterpret_cast<const bf16x8*>(pB + 2 * 16 * DIM + ko);     \
        db[3] = *reinterpret_cast<const bf16x8*>(pB + 3 * 16 * DIM + ko);     \
    }
#define MFMAF(a, b)                                                           \
    {                                                                         \
        _Pragma("unroll") for (int m = 0; m < 4; m++)                         \
            _Pragma("unroll") for (int n = 0; n < 4; n++)                     \
                acc[m][n] = __builtin_amdgcn_mfma_f32_16x16x32_bf16(          \
                    a[m], b[n], acc[m][n], 0, 0, 0);                          \
    }

    // 4 K32-steps, 2 named register sets, 2 LOADFs (16 loads) in flight
    bf16x8 a0[4], b0[4], a1[4], b1[4];
    LOADF(a0, b0, 0)
    LOADF(a1, b1, 1)
    MFMAF(a0, b0)
    LOADF(a0, b0, 2)
    MFMAF(a1, b1)
    LOADF(a1, b1, 3)
    MFMAF(a0, b0)
    MFMAF(a1, b1)
#undef LOADF
#undef MFMAF

    // ---- cross-wave K-reduction via LDS ----
    // wave w writes its partial acc[m][*] for m != w; then owns strip m = w.
#pragma unroll
    for (int m = 0; m < 4; m++) {
        if (m != wid) {
            int s = (wid < m) ? wid : wid - 1;
#pragma unroll
            for (int n = 0; n < 4; n++) red[m][s][n][lane] = acc[m][n];
        }
    }
    f32x4 facc[4];
#pragma unroll
    for (int n = 0; n < 4; n++) facc[n] = (f32x4){0.f, 0.f, 0.f, 0.f};
#pragma unroll
    for (int m = 0; m < 4; m++) {
        if (m == wid) {
#pragma unroll
            for (int n = 0; n < 4; n++) facc[n] += acc[m][n];
        }
    }
    __syncthreads();
#pragma unroll
    for (int s = 0; s < 3; s++)
#pragma unroll
        for (int n = 0; n < 4; n++) facc[n] += red[wid][s][n][lane];

    // ---- fused epilogue (wave w owns rows rowBase + 16w .. +16) ----
    // C/D layout: col = l15 + 16n, row(in strip) = lg*4 + q
    int   gcol[4], tgj[4];
    float mj[4];
#pragma unroll
    for (int n = 0; n < 4; n++) {
        gcol[n] = colBase + n * 16 + l15;
        tgj[n]  = tgt[gcol[n]];
        mj[n]   = mag[gcol[n]];
    }
    int   grow[4], tgi[4];
    float mi[4];
#pragma unroll
    for (int q = 0; q < 4; q++) {
        grow[q] = rowBase + wid * 16 + lg * 4 + q;
        tgi[q]  = tgt[grow[q]];
        mi[q]   = mag[grow[q]];
    }

    float negrow[4] = {0.f, 0.f, 0.f, 0.f};
    float negcol[4] = {0.f, 0.f, 0.f, 0.f};
    int mycnt = 0;
#pragma unroll
    for (int n = 0; n < 4; n++)
#pragma unroll
        for (int q = 0; q < 4; q++) {
            float sim  = facc[n][q];
            float d2   = mi[q] + mj[n] - 2.f * sim;
            float dist = d2 > 0.f ? sqrtf(d2) : 0.f;
            if (tgi[q] != tgj[n]) {
                if (dist != 0.f) {
                    float e = __expf(1.0f - dist);
                    negrow[q] += e;
                    if (offd) negcol[n] += e;
                }
            } else if (grow[q] < gcol[n]) {
                mycnt++;
            }
        }

    // row-side: reduce across the 16 l15 lanes, 1 atomic/row
#pragma unroll
    for (int q = 0; q < 4; q++) {
        float v = negrow[q];
        v += __shfl_xor(v, 1); v += __shfl_xor(v, 2);
        v += __shfl_xor(v, 4); v += __shfl_xor(v, 8);
        if (l15 == 0) atomicAdd(&row_neg[grow[q]], v);
    }
    // col-side (off-diagonal tiles): reduce across lg groups, 1 atomic/col
    if (offd) {
#pragma unroll
        for (int n = 0; n < 4; n++) {
            float v = negcol[n];
            v += __shfl_xor(v, 16); v += __shfl_xor(v, 32);
            if (lg == 0) atomicAdd(&row_neg[gcol[n]], v);
        }
    }

    // compact positive (i<j) pairs
    if (mycnt) {
        unsigned int base = atomicAdd(pair_cnt, (unsigned int)mycnt);
        unsigned int off = 0;
#pragma unroll
        for (int n = 0; n < 4; n++)
#pragma unroll
            for (int q = 0; q < 4; q++) {
                if (tgi[q] == tgj[n] && grow[q] < gcol[n]) {
                    unsigned int idx = base + off;
                    if (idx < cap) {
                        float sim  = facc[n][q];
                        float d2   = mi[q] + mj[n] - 2.f * sim;
                        float dist = d2 > 0.f ? sqrtf(d2) : 0.f;
                        pairs[idx * 3 + 0] = grow[q];
                        pairs[idx * 3 + 1] = gcol[n];
                        pairs[idx * 3 + 2] = __float_as_int(dist);
                    }
                    off++;
                }
            }
    }
}

__global__ void pair_kernel(const int* __restrict__ pairs,
                            const unsigned int* __restrict__ pair_cnt,
                            const float* __restrict__ row_neg,
                            unsigned int cap, double* __restrict__ loss) {
    __shared__ double red[256];
    unsigned int n = *pair_cnt;
    if (n > cap) n = cap;
    double local = 0.0;
    for (unsigned int p = blockIdx.x * blockDim.x + threadIdx.x; p < n;
         p += gridDim.x * blockDim.x) {
        int i = pairs[3 * p], j = pairs[3 * p + 1];
        float d = __int_as_float(pairs[3 * p + 2]);
        float J = logf(row_neg[i] + row_neg[j]) + d;
        if (J > 0.f) local += (double)J * (double)J;
    }
    red[threadIdx.x] = local;
    __syncthreads();
    for (int s = 128; s; s >>= 1) {
        if (threadIdx.x < (unsigned)s) red[threadIdx.x] += red[threadIdx.x + s];
        __syncthreads();
    }
    if (threadIdx.x == 0) atomicAdd(loss, red[0]);
}

__global__ void fin_kernel(const double* __restrict__ loss,
                           const unsigned int* __restrict__ pair_cnt,
                           float* __restrict__ out) {
    out[0] = (float)(*loss / (2.0 * (double)(*pair_cnt)));
}

extern "C" void kernel_launch(void* const* d_in, const int* in_sizes, int n_in,
                              void* d_out, int out_size, void* d_ws, size_t ws_size,
                              hipStream_t stream) {
    const float* X = (const float*)d_in[0];
    const int* tgt = (const int*)d_in[1];
    float* out = (float*)d_out;

    char* ws = (char*)d_ws;
    float* mag             = (float*)(ws + 0);
    float* row_neg         = (float*)(ws + 16384);
    double* loss           = (double*)(ws + 32768);
    unsigned int* pair_cnt = (unsigned int*)(ws + 32776);
    unsigned short* Xb     = (unsigned short*)(ws + XB_OFF);
    int* pairs             = (int*)(ws + PAIR_OFF);
    unsigned int cap = 0;
    if (ws_size > PAIR_OFF + 12) cap = (unsigned int)((ws_size - PAIR_OFF) / 12);

    hipMemsetAsync(ws + 16384, 0, 16400, stream);  // row_neg, loss, pair_cnt

    prep_kernel<<<NROWS / 4, 256, 0, stream>>>(X, Xb, mag);

    sim_ksplit<<<NBLK, 256, 0, stream>>>(Xb, tgt, mag, row_neg, pair_cnt, pairs, cap);

    pair_kernel<<<256, 256, 0, stream>>>(pairs, pair_cnt, row_neg, cap, loss);

    fin_kernel<<<1, 1, 0, stream>>>(loss, pair_cnt, out);
}

// Round 6
// 77.075 us; speedup vs baseline: 1.9087x; 1.9087x over previous
//
#include <hip/hip_runtime.h>
#include <math.h>

#define NROWS 4096
#define DIM   512
#define BM    128
#define BK    64
#define NKT   (DIM / BK)        // 8
#define NTILE (NROWS / BM)      // 32
#define NBLK  (NTILE * (NTILE + 1) / 2)  // 528 triangular blocks

typedef __attribute__((ext_vector_type(4))) float f32x4;
typedef __attribute__((ext_vector_type(8))) short bf16x8;

// ws layout (bytes):
// [0,      16384)    float mag[4096]
// [16384,  32768)    float row_neg[4096]
// [32768,  32776)    double loss
// [32776,  32780)    unsigned int pair_cnt
// [32800,  294944)   ushort part[32][4096]   (bf16 per-tile negsum partials)
// [294944, 4489248)  unsigned short Xb[4096*512]  (bf16 copy of X)
// [4489248, ...)     pairs: uint2 {(i<<16)|j, float_bits(dist)}  8 B each
#define PART_OFF 32800
#define XB_OFF   (PART_OFF + NTILE * NROWS * 2)          // 294944
#define PAIR_OFF (XB_OFF + NROWS * DIM * 2)              // 4489248

__device__ inline unsigned short f2bf(float f) {
    unsigned int u = __float_as_uint(f);
    unsigned int r = (u + 0x7fffu + ((u >> 16) & 1u)) >> 16;   // RTNE
    return (unsigned short)r;
}
__device__ inline float bf2f(unsigned short u) {
    return __uint_as_float((unsigned int)u << 16);
}

// fused: bf16 convert + row sq-norms (reads X once)
__global__ void prep_kernel(const float* __restrict__ X,
                            unsigned short* __restrict__ Xb,
                            float* __restrict__ mag) {
    int row  = blockIdx.x * 4 + (threadIdx.x >> 6);
    int lane = threadIdx.x & 63;
    const float4* p = reinterpret_cast<const float4*>(X + (size_t)row * DIM);
    short4* o = reinterpret_cast<short4*>(Xb + (size_t)row * DIM);
    float s = 0.f;
#pragma unroll
    for (int q = lane; q < DIM / 4; q += 64) {
        float4 v = p[q];
        s += v.x * v.x + v.y * v.y + v.z * v.z + v.w * v.w;
        short4 b;
        b.x = (short)f2bf(v.x); b.y = (short)f2bf(v.y);
        b.z = (short)f2bf(v.z); b.w = (short)f2bf(v.w);
        o[q] = b;
    }
#pragma unroll
    for (int off = 32; off; off >>= 1) s += __shfl_down(s, off);
    if (lane == 0) mag[row] = s;
}

__global__ __launch_bounds__(256) void sim_mfma(
        const unsigned short* __restrict__ Xb, const int* __restrict__ tgt,
        const float* __restrict__ mag, unsigned short* __restrict__ part,
        unsigned int* __restrict__ pair_cnt, uint2* __restrict__ pairs,
        unsigned int cap) {
    __shared__ unsigned short As[BM * BK];   // 16 KB
    __shared__ unsigned short Bs[BM * BK];   // 16 KB
    __shared__ float rowbuf[2][BM];          // [wc][row-local]
    __shared__ float colbuf[2][BM];          // [wr][col-local]
    __shared__ unsigned int scan[8];         // wave totals + base

    const int tid  = threadIdx.x;
    const int lane = tid & 63;
    const int wid  = tid >> 6;        // 4 waves: 2x2 of 64x64
    const int wr   = wid >> 1, wc = wid & 1;
    const int l15  = lane & 15;
    const int lg   = lane >> 4;       // 0..3

    // triangular block mapping: t -> (bi, bj), bi <= bj (NTILE=32)
    int t = blockIdx.x;
    int bi = (int)((65.0f - sqrtf(4225.0f - 8.0f * (float)t)) * 0.5f);
    if (bi < 0) bi = 0;
    if (bi > NTILE - 1) bi = NTILE - 1;
    while ((65 * (bi + 1) - (bi + 1) * (bi + 1)) / 2 <= t) bi++;
    while ((65 * bi - bi * bi) / 2 > t) bi--;
    int bj = bi + (t - (65 * bi - bi * bi) / 2);
    const int rowBase = bi * BM;
    const int colBase = bj * BM;
    const bool offd = (bi != bj);

    f32x4 acc[4][4];
#pragma unroll
    for (int m = 0; m < 4; m++)
#pragma unroll
        for (int n = 0; n < 4; n++) acc[m][n] = (f32x4){0.f, 0.f, 0.f, 0.f};

    // single-buffer m97-style K-loop: sync / stage / sync / compute
    for (int kt = 0; kt < NKT; kt++) {
        const int k0 = kt * BK;
        __syncthreads();   // previous iteration's reads done before overwrite
        // LDS slot (row r, chunk s) holds global chunk s^(r&7) (rule #21)
#pragma unroll
        for (int c = 0; c < 4; c++) {
            int chunkBase = (c * 4 + wid) * 64;      // wave-uniform
            int idx = chunkBase + lane;              // 0..1023
            int r   = idx >> 3;
            int ch  = idx & 7;
            int gch = ch ^ (r & 7);
            const unsigned short* ga = Xb + (size_t)(rowBase + r) * DIM + k0 + gch * 8;
            __builtin_amdgcn_global_load_lds(
                (const __attribute__((address_space(1))) void*)ga,
                (__attribute__((address_space(3))) void*)(As + chunkBase * 8),
                16, 0, 0);
            const unsigned short* gb = Xb + (size_t)(colBase + r) * DIM + k0 + gch * 8;
            __builtin_amdgcn_global_load_lds(
                (const __attribute__((address_space(1))) void*)gb,
                (__attribute__((address_space(3))) void*)(Bs + chunkBase * 8),
                16, 0, 0);
        }
        __syncthreads();   // compiler drains vmcnt before barrier

#pragma unroll
        for (int ksub = 0; ksub < 2; ksub++) {
            bf16x8 af[4], bf[4];
#pragma unroll
            for (int m = 0; m < 4; m++) {
                int ra = wr * 64 + m * 16 + l15;
                int ch = (ksub * 4 + lg) ^ (ra & 7);
                af[m] = *reinterpret_cast<const bf16x8*>(&As[ra * BK + ch * 8]);
            }
#pragma unroll
            for (int n = 0; n < 4; n++) {
                int rb = wc * 64 + n * 16 + l15;
                int ch = (ksub * 4 + lg) ^ (rb & 7);
                bf[n] = *reinterpret_cast<const bf16x8*>(&Bs[rb * BK + ch * 8]);
            }
#pragma unroll
            for (int m = 0; m < 4; m++)
#pragma unroll
                for (int n = 0; n < 4; n++)
                    acc[m][n] = __builtin_amdgcn_mfma_f32_16x16x32_bf16(
                        af[m], bf[n], acc[m][n], 0, 0, 0);
        }
    }

    // ---- fused epilogue ----
    // C/D layout: col = lane&15, row = (lane>>4)*4 + reg
    int   gcol[4], tgj[4];
    float mj[4];
#pragma unroll
    for (int n = 0; n < 4; n++) {
        gcol[n] = colBase + wc * 64 + n * 16 + l15;
        tgj[n]  = tgt[gcol[n]];
        mj[n]   = mag[gcol[n]];
    }
    int   grow[4][4], tgi[4][4];
    float mi[4][4];
#pragma unroll
    for (int m = 0; m < 4; m++)
#pragma unroll
        for (int q = 0; q < 4; q++) {
            grow[m][q] = rowBase + wr * 64 + m * 16 + lg * 4 + q;
            tgi[m][q]  = tgt[grow[m][q]];
            mi[m][q]   = mag[grow[m][q]];
        }

    float negrow[4][4];
    float negcol[4] = {0.f, 0.f, 0.f, 0.f};
#pragma unroll
    for (int m = 0; m < 4; m++)
#pragma unroll
        for (int q = 0; q < 4; q++) negrow[m][q] = 0.f;

    int mycnt = 0;
#pragma unroll
    for (int m = 0; m < 4; m++)
#pragma unroll
        for (int n = 0; n < 4; n++)
#pragma unroll
            for (int q = 0; q < 4; q++) {
                float sim  = acc[m][n][q];
                float d2   = mi[m][q] + mj[n] - 2.f * sim;
                float dist = d2 > 0.f ? sqrtf(d2) : 0.f;
                if (tgi[m][q] != tgj[n]) {
                    if (dist != 0.f) {
                        float e = __expf(1.0f - dist);
                        negrow[m][q] += e;
                        if (offd) negcol[n] += e;
                    }
                } else if (grow[m][q] < gcol[n]) {
                    mycnt++;
                }
            }

    __syncthreads();   // LDS (As/Bs) reads done; safe to reuse shared space

    // row-side: reduce across the 16 l15 lanes -> rowbuf[wc][row-local]
#pragma unroll
    for (int m = 0; m < 4; m++)
#pragma unroll
        for (int q = 0; q < 4; q++) {
            float v = negrow[m][q];
            v += __shfl_xor(v, 1); v += __shfl_xor(v, 2);
            v += __shfl_xor(v, 4); v += __shfl_xor(v, 8);
            if (l15 == 0) rowbuf[wc][wr * 64 + m * 16 + lg * 4 + q] = v;
        }
    // col-side: reduce across the 4 lg groups -> colbuf[wr][col-local]
#pragma unroll
    for (int n = 0; n < 4; n++) {
        float v = negcol[n];
        v += __shfl_xor(v, 16); v += __shfl_xor(v, 32);
        if (lg == 0) colbuf[wr][wc * 64 + n * 16 + l15] = v;
    }

    // pair-count scan: wave-level inclusive prefix, then block scan
    unsigned int pc = (unsigned int)mycnt;
    unsigned int incl = pc;
#pragma unroll
    for (int d = 1; d < 64; d <<= 1) {
        unsigned int tshf = __shfl_up(incl, d);
        if (lane >= d) incl += tshf;
    }
    if (lane == 63) scan[wid] = incl;
    __syncthreads();

    // collision-free partial stores: slot part[k][r] written by exactly 1 block
    if (tid < BM) {
        float rv = rowbuf[0][tid] + rowbuf[1][tid];
        part[(size_t)bj * NROWS + rowBase + tid] = f2bf(rv);
        if (offd) {
            float cv = colbuf[0][tid] + colbuf[1][tid];
            part[(size_t)bi * NROWS + colBase + tid] = f2bf(cv);
        }
    }

    unsigned int woff = 0;
#pragma unroll
    for (int w = 0; w < 4; w++)
        if (w < wid) woff += scan[w];
    unsigned int btot = scan[0] + scan[1] + scan[2] + scan[3];
    if (tid == 0) scan[4] = btot ? atomicAdd(pair_cnt, btot) : 0u;
    __syncthreads();
    unsigned int mybase = scan[4] + woff + (incl - pc);

    if (pc) {
        unsigned int idx = mybase;
#pragma unroll
        for (int m = 0; m < 4; m++)
#pragma unroll
            for (int n = 0; n < 4; n++)
#pragma unroll
                for (int q = 0; q < 4; q++) {
                    if (tgi[m][q] == tgj[n] && grow[m][q] < gcol[n]) {
                        if (idx < cap) {
                            float sim  = acc[m][n][q];
                            float d2   = mi[m][q] + mj[n] - 2.f * sim;
                            float dist = d2 > 0.f ? sqrtf(d2) : 0.f;
                            uint2 e;
                            e.x = ((unsigned int)grow[m][q] << 16) | (unsigned int)gcol[n];
                            e.y = (unsigned int)__float_as_int(dist);
                            pairs[idx] = e;
                        }
                        idx++;
                    }
                }
    }
}

// row_neg[r] = sum over 32 tile-partials (bf16 -> f32)
__global__ void reduce_kernel(const unsigned short* __restrict__ part,
                              float* __restrict__ row_neg) {
    int r = blockIdx.x * 256 + threadIdx.x;
    float s = 0.f;
#pragma unroll
    for (int k = 0; k < NTILE; k++) s += bf2f(part[(size_t)k * NROWS + r]);
    row_neg[r] = s;
}

__global__ void pair_kernel(const uint2* __restrict__ pairs,
                            const unsigned int* __restrict__ pair_cnt,
                            const float* __restrict__ row_neg,
                            unsigned int cap, double* __restrict__ loss) {
    __shared__ double red[256];
    unsigned int n = *pair_cnt;
    if (n > cap) n = cap;
    double local = 0.0;
    for (unsigned int p = blockIdx.x * blockDim.x + threadIdx.x; p < n;
         p += gridDim.x * blockDim.x) {
        uint2 e = pairs[p];
        int i = (int)(e.x >> 16), j = (int)(e.x & 0xffffu);
        float d = __int_as_float((int)e.y);
        float J = logf(row_neg[i] + row_neg[j]) + d;
        if (J > 0.f) local += (double)J * (double)J;
    }
    red[threadIdx.x] = local;
    __syncthreads();
    for (int s = 128; s; s >>= 1) {
        if (threadIdx.x < (unsigned)s) red[threadIdx.x] += red[threadIdx.x + s];
        __syncthreads();
    }
    if (threadIdx.x == 0) atomicAdd(loss, red[0]);
}

__global__ void fin_kernel(const double* __restrict__ loss,
                           const unsigned int* __restrict__ pair_cnt,
                           float* __restrict__ out) {
    out[0] = (float)(*loss / (2.0 * (double)(*pair_cnt)));
}

extern "C" void kernel_launch(void* const* d_in, const int* in_sizes, int n_in,
                              void* d_out, int out_size, void* d_ws, size_t ws_size,
                              hipStream_t stream) {
    const float* X = (const float*)d_in[0];
    const int* tgt = (const int*)d_in[1];
    float* out = (float*)d_out;

    char* ws = (char*)d_ws;
    float* mag             = (float*)(ws + 0);
    float* row_neg         = (float*)(ws + 16384);
    double* loss           = (double*)(ws + 32768);
    unsigned int* pair_cnt = (unsigned int*)(ws + 32776);
    unsigned short* part   = (unsigned short*)(ws + PART_OFF);
    unsigned short* Xb     = (unsigned short*)(ws + XB_OFF);
    uint2* pairs           = (uint2*)(ws + PAIR_OFF);
    unsigned int cap = 0;
    if (ws_size > PAIR_OFF + 8) cap = (unsigned int)((ws_size - PAIR_OFF) / 8);

    hipMemsetAsync(ws + 32768, 0, 16, stream);  // loss + pair_cnt

    prep_kernel<<<NROWS / 4, 256, 0, stream>>>(X, Xb, mag);

    sim_mfma<<<NBLK, 256, 0, stream>>>(Xb, tgt, mag, part, pair_cnt, pairs, cap);

    reduce_kernel<<<NROWS / 256, 256, 0, stream>>>(part, row_neg);

    pair_kernel<<<256, 256, 0, stream>>>(pairs, pair_cnt, row_neg, cap, loss);

    fin_kernel<<<1, 1, 0, stream>>>(loss, pair_cnt, out);
}